// Round 1
// baseline (194.539 us; speedup 1.0000x reference)
//
#include <hip/hip_runtime.h>
#include <stdint.h>

#define N_NODES 100000
#define DF 128
#define K_NBR 15
#define LN_EPS 1e-5f

typedef __attribute__((ext_vector_type(8))) short bf16x8;
typedef __attribute__((ext_vector_type(4))) float f32x4;

static __device__ __forceinline__ unsigned short f2bf(float f) {
    union { float f; uint32_t u; } v; v.f = f;
    uint32_t u = v.u;
    uint32_t r = u + 0x7FFFu + ((u >> 16) & 1u);   // RNE
    return (unsigned short)(r >> 16);
}

// Block: 256 threads = 4 waves, 64 nodes per block.
// LDS: Wb (bf16 [n=out_d][k=in_j], XOR-swizzled) 32KB + At (bf16 [m=node][k], swizzled) 16KB.
__global__ __launch_bounds__(256, 3)
void nagg_kernel(const float* __restrict__ nf,
                 const int* __restrict__ nbr,
                 const int* __restrict__ cnts,
                 const float* __restrict__ W,
                 const float* __restrict__ bias,
                 const float* __restrict__ lnw,
                 const float* __restrict__ lnb,
                 float* __restrict__ out)
{
    __shared__ __align__(16) unsigned char smem[32768 + 16384];
    unsigned char* Wb = smem;
    unsigned char* At = smem + 32768;

    const int tid  = threadIdx.x;
    const int lane = tid & 63;
    const int w    = tid >> 6;       // wave 0..3
    const int base = blockIdx.x * 64;

    // ---- Phase 0: W fp32 [d][j] -> LDS bf16 [n][k], XOR-swizzled ----
    {
        const float4* W4 = (const float4*)W;
        #pragma unroll
        for (int it = 0; it < 16; ++it) {
            int e = it * 1024 + tid * 4;     // element index into W (row-major [d][j])
            float4 v = W4[e >> 2];
            int n = e >> 7;                  // out dim
            int k = e & 127;                 // in dim
            ushort4 h;
            h.x = f2bf(v.x); h.y = f2bf(v.y); h.z = f2bf(v.z); h.w = f2bf(v.w);
            int byte = (n * 256 + k * 2) ^ ((n & 7) << 4);
            *(ushort4*)(Wb + byte) = h;
        }
    }

    // ---- Phase 1: neighbor aggregation -> At (bf16, swizzled) ----
    {
        const int g = lane >> 4;   // neighbor-slot group 0..3
        const int s = lane & 15;   // feature sub-lane: features s*8 .. s*8+7
        for (int t = 0; t < 16; ++t) {
            int m = w * 16 + t;
            int i = base + m;
            bool valid = (i < N_NODES);
            int cnt = valid ? cnts[i] : 0;
            int myidx = (valid && lane < K_NBR) ? nbr[i * K_NBR + lane] : 0;

            float acc[8] = {0.f,0.f,0.f,0.f,0.f,0.f,0.f,0.f};
            #pragma unroll
            for (int st = 0; st < 4; ++st) {
                int k = st * 4 + g;                  // 0..15 (15 always invalid)
                int idx = __shfl(myidx, k & 15);
                if (k < cnt) {
                    const float4* p = (const float4*)(nf + (size_t)idx * DF + s * 8);
                    float4 u0 = p[0];
                    float4 u1 = p[1];
                    acc[0]+=u0.x; acc[1]+=u0.y; acc[2]+=u0.z; acc[3]+=u0.w;
                    acc[4]+=u1.x; acc[5]+=u1.y; acc[6]+=u1.z; acc[7]+=u1.w;
                }
            }
            #pragma unroll
            for (int j = 0; j < 8; ++j) {
                acc[j] += __shfl_xor(acc[j], 16);
                acc[j] += __shfl_xor(acc[j], 32);
            }
            if (g == 0) {
                float inv = 1.0f / (float)(cnt > 0 ? cnt : 1);
                uint4 pk;
                pk.x = (uint)f2bf(acc[0]*inv) | ((uint)f2bf(acc[1]*inv) << 16);
                pk.y = (uint)f2bf(acc[2]*inv) | ((uint)f2bf(acc[3]*inv) << 16);
                pk.z = (uint)f2bf(acc[4]*inv) | ((uint)f2bf(acc[5]*inv) << 16);
                pk.w = (uint)f2bf(acc[6]*inv) | ((uint)f2bf(acc[7]*inv) << 16);
                int byte = (m * 256 + s * 16) ^ ((m & 7) << 4);
                *(uint4*)(At + byte) = pk;
            }
        }
    }

    __syncthreads();

    // ---- Phase 2: GEMM  Out[m][n] = sum_k A[m][k] * W[n][k]  via mfma 16x16x32 ----
    const int l15 = lane & 15;
    const int q   = lane >> 4;

    bf16x8 afr[4];
    #pragma unroll
    for (int kk = 0; kk < 4; ++kk) {
        int m = w * 16 + l15;
        int byte = (m * 256 + kk * 64 + q * 16) ^ ((m & 7) << 4);
        afr[kk] = *(const bf16x8*)(At + byte);
    }

    f32x4 acc[8];
    #pragma unroll
    for (int nb = 0; nb < 8; ++nb) acc[nb] = (f32x4){0.f,0.f,0.f,0.f};

    #pragma unroll
    for (int nb = 0; nb < 8; ++nb) {
        #pragma unroll
        for (int kk = 0; kk < 4; ++kk) {
            int n = nb * 16 + l15;
            int byte = (n * 256 + kk * 64 + q * 16) ^ ((n & 7) << 4);
            bf16x8 bfr = *(const bf16x8*)(Wb + byte);
            acc[nb] = __builtin_amdgcn_mfma_f32_16x16x32_bf16(afr[kk], bfr, acc[nb], 0, 0, 0);
        }
    }

    // ---- Phase 3: epilogue: bias + residual + LN + ReLU + where ----
    float bv[8], lwv[8], lbv[8];
    #pragma unroll
    for (int nb = 0; nb < 8; ++nb) {
        int c = nb * 16 + l15;
        bv[nb]  = bias[c];
        lwv[nb] = lnw[c];
        lbv[nb] = lnb[c];
    }

    #pragma unroll
    for (int r = 0; r < 4; ++r) {
        int mloc = q * 4 + r;               // C/D row = (lane>>4)*4 + reg
        int node = base + w * 16 + mloc;
        if (node < N_NODES) {
            int cnt = cnts[node];
            float vals[8], nfv[8];
            float s = 0.f, sq = 0.f;
            #pragma unroll
            for (int nb = 0; nb < 8; ++nb) {
                int c = nb * 16 + l15;
                float nv = nf[(size_t)node * DF + c];
                float comb = nv + acc[nb][r] + bv[nb];
                nfv[nb]  = nv;
                vals[nb] = comb;
                s  += comb;
                sq += comb * comb;
            }
            #pragma unroll
            for (int off = 1; off < 16; off <<= 1) {
                s  += __shfl_xor(s,  off);
                sq += __shfl_xor(sq, off);
            }
            float mu   = s  * (1.0f / 128.0f);
            float var  = sq * (1.0f / 128.0f) - mu * mu;
            float rstd = rsqrtf(var + LN_EPS);
            #pragma unroll
            for (int nb = 0; nb < 8; ++nb) {
                int c = nb * 16 + l15;
                float nrm = (vals[nb] - mu) * rstd * lwv[nb] + lbv[nb];
                float rel = fmaxf(nrm, 0.0f);
                out[(size_t)node * DF + c] = (cnt > 0) ? rel : nfv[nb];
            }
        }
    }
}

extern "C" void kernel_launch(void* const* d_in, const int* in_sizes, int n_in,
                              void* d_out, int out_size, void* d_ws, size_t ws_size,
                              hipStream_t stream) {
    const float* nf   = (const float*)d_in[0];
    const int*   nbr  = (const int*)d_in[1];
    const int*   cnts = (const int*)d_in[2];
    const float* W    = (const float*)d_in[3];
    const float* b    = (const float*)d_in[4];
    const float* lnw  = (const float*)d_in[5];
    const float* lnb  = (const float*)d_in[6];
    float* out = (float*)d_out;

    int blocks = (N_NODES + 63) / 64;   // 1563
    nagg_kernel<<<blocks, 256, 0, stream>>>(nf, nbr, cnts, W, b, lnw, lnb, out);
}

// Round 2
// 173.500 us; speedup vs baseline: 1.1213x; 1.1213x over previous
//
#include <hip/hip_runtime.h>
#include <stdint.h>

#define NN 100000
#define DF 128
#define KN 15
#define LN_EPS 1e-5f

typedef __attribute__((ext_vector_type(8))) short bf16x8;
typedef __attribute__((ext_vector_type(4))) float f32x4;

static __device__ __forceinline__ unsigned short f2bf(float f) {
    union { float f; uint32_t u; } v; v.f = f;
    uint32_t r = v.u + 0x7FFFu + ((v.u >> 16) & 1u);   // RNE
    return (unsigned short)(r >> 16);
}

// 512 threads = 8 waves, 128 nodes/block.
// LDS: Wb 32KB (bf16 [n][k] XOR-swizzled) + At 32KB (bf16 [m][k] swizzled)
//      + idx 8KB + cnt 0.5KB  = 74.2KB -> 2 blocks/CU -> 16 waves/CU.
__global__ __launch_bounds__(512, 4)
void nagg_kernel(const float* __restrict__ nf,
                 const int* __restrict__ nbr,
                 const int* __restrict__ cnts,
                 const float* __restrict__ W,
                 const float* __restrict__ bias,
                 const float* __restrict__ lnw,
                 const float* __restrict__ lnb,
                 float* __restrict__ out)
{
    __shared__ __align__(16) unsigned char WbS[32768];
    __shared__ __align__(16) unsigned char AtS[32768];
    __shared__ int idxS[128 * 16];
    __shared__ int cntS[128];

    const int tid  = threadIdx.x;
    const int lane = tid & 63;
    const int w    = tid >> 6;          // wave 0..7
    const int base = blockIdx.x * 128;

    // ---- Phase 0a: W fp32 [d][j] -> LDS bf16 [n][k], XOR-swizzled ----
    {
        const float4* W4 = (const float4*)W;
        #pragma unroll
        for (int it = 0; it < 8; ++it) {
            int e = it * 2048 + tid * 4;      // element index into W
            float4 v = W4[e >> 2];
            int n = e >> 7;                   // out dim
            int k = e & 127;                  // in dim
            ushort4 h;
            h.x = f2bf(v.x); h.y = f2bf(v.y); h.z = f2bf(v.z); h.w = f2bf(v.w);
            *(ushort4*)(WbS + ((n * 256 + k * 2) ^ ((n & 7) << 4))) = h;
        }
    }

    // ---- Phase 0b: per-wave staging of this wave's 16 nodes' idx + cnt ----
    {
        if (lane < 16) {
            int m = w * 16 + lane;
            int node = base + m;
            cntS[m] = (node < NN) ? cnts[node] : 0;
        }
        #pragma unroll
        for (int it = 0; it < 4; ++it) {
            int e = it * 64 + lane;           // 0..255, want < 240
            if (e < 240) {
                int mm = e / 15, kk = e - mm * 15;
                int m = w * 16 + mm;
                int node = base + m;
                idxS[m * 16 + kk] = (node < NN) ? nbr[(size_t)node * KN + kk] : 0;
            }
        }
    }
    // per-wave LDS writes read by same wave: in-order DS pipeline, no barrier needed

    // ---- Phase 1: neighbor aggregation -> At (bf16, swizzled) ----
    {
        const int g = lane >> 4;   // neighbor-slot group 0..3
        const int s = lane & 15;   // feature sub-lane: features s*8 .. s*8+7
        #pragma unroll 2
        for (int t = 0; t < 16; ++t) {
            int m = w * 16 + t;
            int cnt = cntS[m];
            float acc[8] = {0.f,0.f,0.f,0.f,0.f,0.f,0.f,0.f};
            #pragma unroll
            for (int st = 0; st < 4; ++st) {
                int k = st * 4 + g;                  // 0..15 (slot 15 always invalid)
                int idx = idxS[m * 16 + (k & 15)];
                if (k < cnt) {
                    const float4* p = (const float4*)(nf + (size_t)idx * DF + s * 8);
                    float4 u0 = p[0];
                    float4 u1 = p[1];
                    acc[0]+=u0.x; acc[1]+=u0.y; acc[2]+=u0.z; acc[3]+=u0.w;
                    acc[4]+=u1.x; acc[5]+=u1.y; acc[6]+=u1.z; acc[7]+=u1.w;
                }
            }
            #pragma unroll
            for (int j = 0; j < 8; ++j) {
                acc[j] += __shfl_xor(acc[j], 16);
                acc[j] += __shfl_xor(acc[j], 32);
            }
            if (g == 0) {
                float inv = 1.0f / (float)(cnt > 0 ? cnt : 1);
                uint4 pk;
                pk.x = (uint)f2bf(acc[0]*inv) | ((uint)f2bf(acc[1]*inv) << 16);
                pk.y = (uint)f2bf(acc[2]*inv) | ((uint)f2bf(acc[3]*inv) << 16);
                pk.z = (uint)f2bf(acc[4]*inv) | ((uint)f2bf(acc[5]*inv) << 16);
                pk.w = (uint)f2bf(acc[6]*inv) | ((uint)f2bf(acc[7]*inv) << 16);
                *(uint4*)(AtS + ((m * 256 + s * 16) ^ ((m & 7) << 4))) = pk;
            }
        }
    }

    __syncthreads();   // Wb (all waves) + At visibility for phase 2

    // ---- Phase 2: Out[m][n] = sum_k A[m][k] * W[n][k] via mfma 16x16x32 ----
    const int l15 = lane & 15;
    const int q   = lane >> 4;

    bf16x8 afr[4];
    #pragma unroll
    for (int kk = 0; kk < 4; ++kk) {
        int m = w * 16 + l15;
        afr[kk] = *(const bf16x8*)(AtS + ((m * 256 + kk * 64 + q * 16) ^ ((m & 7) << 4)));
    }

    f32x4 acc[8];
    #pragma unroll
    for (int nb = 0; nb < 8; ++nb) acc[nb] = (f32x4){0.f,0.f,0.f,0.f};

    #pragma unroll
    for (int nb = 0; nb < 8; ++nb) {
        #pragma unroll
        for (int kk = 0; kk < 4; ++kk) {
            int n = nb * 16 + l15;
            bf16x8 bfr = *(const bf16x8*)(WbS + ((n * 256 + kk * 64 + q * 16) ^ ((n & 7) << 4)));
            acc[nb] = __builtin_amdgcn_mfma_f32_16x16x32_bf16(afr[kk], bfr, acc[nb], 0, 0, 0);
        }
    }

    // ---- Phase 3: bias + residual + LN + ReLU + where ----
    float bv[8], lwv[8], lbv[8];
    #pragma unroll
    for (int nb = 0; nb < 8; ++nb) {
        int c = nb * 16 + l15;
        bv[nb]  = bias[c];
        lwv[nb] = lnw[c];
        lbv[nb] = lnb[c];
    }

    #pragma unroll
    for (int r = 0; r < 4; ++r) {
        int mloc = q * 4 + r;               // C/D row = (lane>>4)*4 + reg
        int m = w * 16 + mloc;
        int node = base + m;
        if (node < NN) {
            int cnt = cntS[m];
            float vals[8], nfv[8];
            float s = 0.f, sq = 0.f;
            #pragma unroll
            for (int nb = 0; nb < 8; ++nb) {
                int c = nb * 16 + l15;
                float nv = nf[(size_t)node * DF + c];
                float comb = nv + acc[nb][r] + bv[nb];
                nfv[nb]  = nv;
                vals[nb] = comb;
                s  += comb;
                sq += comb * comb;
            }
            #pragma unroll
            for (int off = 1; off < 16; off <<= 1) {
                s  += __shfl_xor(s,  off);
                sq += __shfl_xor(sq, off);
            }
            float mu   = s  * (1.0f / 128.0f);
            float var  = sq * (1.0f / 128.0f) - mu * mu;
            float rstd = rsqrtf(var + LN_EPS);
            #pragma unroll
            for (int nb = 0; nb < 8; ++nb) {
                int c = nb * 16 + l15;
                float nrm = (vals[nb] - mu) * rstd * lwv[nb] + lbv[nb];
                float rel = fmaxf(nrm, 0.0f);
                out[(size_t)node * DF + c] = (cnt > 0) ? rel : nfv[nb];
            }
        }
    }
}

extern "C" void kernel_launch(void* const* d_in, const int* in_sizes, int n_in,
                              void* d_out, int out_size, void* d_ws, size_t ws_size,
                              hipStream_t stream) {
    const float* nf   = (const float*)d_in[0];
    const int*   nbr  = (const int*)d_in[1];
    const int*   cnts = (const int*)d_in[2];
    const float* W    = (const float*)d_in[3];
    const float* b    = (const float*)d_in[4];
    const float* lnw  = (const float*)d_in[5];
    const float* lnb  = (const float*)d_in[6];
    float* out = (float*)d_out;

    int blocks = (NN + 127) / 128;   // 782
    nagg_kernel<<<blocks, 512, 0, stream>>>(nf, nbr, cnts, W, b, lnw, lnb, out);
}